// Round 4
// baseline (1064.116 us; speedup 1.0000x reference)
//
#include <hip/hip_runtime.h>
#include <hip/hip_bf16.h>
#include <hip/hip_fp16.h>

#define B 256
#define L 128
#define F 256
#define S 512
#define G4 1024  // 4*F gate rows

typedef _Float16 f16x8 __attribute__((ext_vector_type(8)));
typedef float f32x4 __attribute__((ext_vector_type(4)));

// fast device transcendentals: v_exp_f32 / v_rcp_f32 based
__device__ __forceinline__ float fast_rcp(float x) { return __builtin_amdgcn_rcpf(x); }
__device__ __forceinline__ float sigf(float x) {
    float e = __expf(-x);
    return fast_rcp(1.0f + e);
}
__device__ __forceinline__ float tanhf_fast(float x) {
    x = fminf(fmaxf(x, -15.0f), 15.0f);
    float e = __expf(-2.0f * x);
    return (1.0f - e) * fast_rcp(1.0f + e);
}

// Prep v5: pack combined W = W_ih + W_hh (fp16) as MFMA A-fragments for
// v_mfma_f32_16x16x32_f16.
// Frag f = T*8 + kf (row-tile T in [0,64), k-frag kf in [0,8)).
// Within a frag: lane l, reg r (2 halves e=2r,2r+1):
//   row = T*16 + (l&15),  k = kf*32 + (l>>4)*8 + 2r + {0,1}
// The SAME lane->k map is used to build B-frags from h in lstm_main, so the
// contraction is correct under any consistent hardware k-relabeling.
__global__ void prep_kernel(const float* __restrict__ Wih,
                            const float* __restrict__ Whh,
                            const float* __restrict__ bih,
                            const float* __restrict__ bhh,
                            uint4* __restrict__ Wpk, float* __restrict__ bias_sum) {
    int e = blockIdx.x * blockDim.x + threadIdx.x;  // 32768 = 512 frags * 64 lanes
    if (e < G4) bias_sum[e] = bih[e] + bhh[e];
    int f = e >> 6, l = e & 63;
    int T = f >> 3, kf = f & 7;
    int row = T * 16 + (l & 15);
    int k0 = kf * 32 + (l >> 4) * 8;
    unsigned pk[4];
    #pragma unroll
    for (int r = 0; r < 4; ++r) {
        int k = k0 + 2 * r;
        float w0 = Wih[(size_t)row * F + k]     + Whh[(size_t)row * F + k];
        float w1 = Wih[(size_t)row * F + k + 1] + Whh[(size_t)row * F + k + 1];
        pk[r] = __builtin_bit_cast(unsigned, __floats2half2_rn(w0, w1));
    }
    Wpk[e] = make_uint4(pk[0], pk[1], pk[2], pk[3]);
}

// init = elu(x[0] @ Wi.T + bi) -> h0, c0 (fp32 in workspace), float4 loads
__global__ void init_kernel(const float* __restrict__ x,
                            const float* __restrict__ Wi,
                            const float* __restrict__ bi,
                            float* __restrict__ h, float* __restrict__ c) {
    __shared__ float4 xs4[L / 4];
    int b = blockIdx.x, j = threadIdx.x;
    if (j < L / 4) xs4[j] = ((const float4*)(x + (size_t)b * L))[j];
    __syncthreads();
    float acc = bi[j];
    const float4* wp = (const float4*)(Wi + (size_t)j * L);
    #pragma unroll 8
    for (int k = 0; k < L / 4; ++k) {
        float4 w = wp[k], xv = xs4[k];
        acc += w.x * xv.x + w.y * xv.y + w.z * xv.z + w.w * xv.w;
    }
    float v = acc > 0.0f ? acc : expm1f(acc);
    h[b * F + j] = v;
    c[b * F + j] = v;
}

// Step 0: gates = last_feat @ W_ih.T + h0 @ W_hh.T + bias (fp32 exact path).
__global__ void step0_kernel(const float* __restrict__ lf,
                             const float* __restrict__ Wih,
                             const float* __restrict__ Whh,
                             const float* __restrict__ bias_sum,
                             float* __restrict__ h, float* __restrict__ c,
                             float* __restrict__ out) {
    __shared__ float vecs[2 * F];            // [inp(256) ; h0(256)]
    __shared__ float partial[3][4][F];
    int b = blockIdx.x, tid = threadIdx.x;
    int j = tid & (F - 1), q = tid >> 8;
    if (q == 0) vecs[j] = lf[(size_t)b * F + j];
    else if (q == 1) vecs[F + j] = h[(size_t)b * F + j];
    __syncthreads();
    const float* mat = (q < 2) ? Wih : Whh;
    int ks = (q & 1) * 128;
    const float4* vp = (const float4*)(&vecs[(q >> 1) * F + ks]);
    float a[4] = {0.f, 0.f, 0.f, 0.f};
    #pragma unroll
    for (int g = 0; g < 4; ++g) {
        const float4* wp = (const float4*)(&mat[(size_t)(g * F + j) * F + ks]);
        float acc = 0.f;
        #pragma unroll 8
        for (int i = 0; i < 32; ++i) {
            float4 w = wp[i], v = vp[i];
            acc += w.x * v.x + w.y * v.y + w.z * v.z + w.w * v.w;
        }
        a[g] = acc;
    }
    if (q > 0) {
        #pragma unroll
        for (int g = 0; g < 4; ++g) partial[q - 1][g][j] = a[g];
    }
    __syncthreads();
    if (q == 0) {
        #pragma unroll
        for (int g = 0; g < 4; ++g) {
            for (int p = 0; p < 3; ++p) a[g] += partial[p][g][j];
            a[g] += bias_sum[g * F + j];
        }
        float c0v = c[(size_t)b * F + j];
        float c1v = sigf(a[1]) * c0v + sigf(a[0]) * tanhf_fast(a[2]);
        float h1v = sigf(a[3]) * tanhf_fast(c1v);
        h[(size_t)b * F + j] = h1v;
        c[(size_t)b * F + j] = c1v;
        out[(size_t)b * F + j] = h1v;  // t=0 row
    }
}

// Main recurrence v5: MFMA matvec. One block of 512 threads (8 waves) per
// batch element. Wave w owns row-tiles [8w, 8w+8) (rows 128w..128w+127).
// Per step: gates(1024) = W(1024x256) @ h(256) via 64 v_mfma_f32_16x16x32_f16
// per wave; h is broadcast across the 16 B-columns so every column of D holds
// the gate value (extraction robust to B/D column layout).
// A-frags: 45/64 per wave register-resident (180 regs -> AGPRs, read by MFMA
// directly: no shuttle), 19/64 streamed from LDS (152 KB, contiguous b128,
// conflict-free). B-frags: 8 ds_read_b128 from packed-half2 hbuf (4 distinct
// addrs/wave, conflict-free broadcast). D rows (l>>4)*4+r (m89-verified map)
// bounce through gbuf; tail = round-0 structure (j=tid>>1, q=0 writes hbuf,
// q=1 does the DEFERRED out-store at the top of the next step).
__launch_bounds__(512, 2)
__global__ void lstm_main(const uint4* __restrict__ Wpk,
                          const float* __restrict__ bias_sum,
                          const float* __restrict__ h_in,
                          const float* __restrict__ c_in,
                          float* __restrict__ out) {
    int b = blockIdx.x;
    int tid = threadIdx.x;
    int w = tid >> 6, l = tid & 63;
    int j = tid >> 1, q = tid & 1;

    __shared__ uint4 lds_ws[152 * 64];   // 8 waves x 19 streamed frags x 64 lanes = 152 KB
    __shared__ uint4 hbuf4[32];          // h as 128 packed half2 (512 B)
    __shared__ float gbuf[G4];           // gate bounce buffer, 4 KB

    // One-time: 45 resident A-frags into registers, 19 streamed frags into LDS.
    uint4 wr[45];
    #pragma unroll
    for (int fi = 0; fi < 45; ++fi) wr[fi] = Wpk[(size_t)(64 * w + fi) * 64 + l];
    #pragma unroll
    for (int s = 0; s < 19; ++s)
        lds_ws[(w * 19 + s) * 64 + l] = Wpk[(size_t)(64 * w + 45 + s) * 64 + l];

    float bias0 = bias_sum[0 * F + j];
    float bias1 = bias_sum[1 * F + j];
    float bias2 = bias_sum[2 * F + j];
    float bias3 = bias_sum[3 * F + j];
    float cj = c_in[(size_t)b * F + j];

    if (tid < 128) {
        float h0 = h_in[(size_t)b * F + 2 * tid];
        float h1 = h_in[(size_t)b * F + 2 * tid + 1];
        ((unsigned*)hbuf4)[tid] = __builtin_bit_cast(unsigned, __floats2half2_rn(h0, h1));
    }
    __syncthreads();

    const int hb = l >> 4;  // B-frag k-quadrant
    float hprev = 0.f;      // deferred out-store value (q==1 path)
    for (int t = 1; t < S; ++t) {
        // deferred store of previous step's h row: drains at bar1, hidden
        // under this step's MFMA phase.
        if (q == 1 && t > 1) {
            __builtin_nontemporal_store(hprev, &out[((size_t)(t - 1) * B + b) * F + j]);
        }
        // Build B-frags once (shared across all 8 row-tiles). Reg r of frag kf
        // holds h pairs kf*16 + hb*4 + r  ==  h[kf*32 + hb*8 + 2r + {0,1}]:
        // same lane->k map as prep's A packing.
        uint4 Bv[8];
        #pragma unroll
        for (int kf = 0; kf < 8; ++kf) Bv[kf] = hbuf4[kf * 4 + hb];

        // MFMA phase: 8 row-tiles as 4 interleaved pairs (breaks acc dep chain).
        #pragma unroll
        for (int p = 0; p < 4; ++p) {
            f32x4 accA = {0.f, 0.f, 0.f, 0.f};
            f32x4 accB = {0.f, 0.f, 0.f, 0.f};
            #pragma unroll
            for (int kf = 0; kf < 8; ++kf) {
                const int fiA = (2 * p) * 8 + kf;      // < 45 for p<=2 -> resident
                const int fiB = (2 * p + 1) * 8 + kf;  // streamed for p>=2 tail
                uint4 a4 = (fiA < 45) ? wr[fiA] : lds_ws[(w * 19 + fiA - 45) * 64 + l];
                uint4 b4 = (fiB < 45) ? wr[fiB] : lds_ws[(w * 19 + fiB - 45) * 64 + l];
                accA = __builtin_amdgcn_mfma_f32_16x16x32_f16(
                    __builtin_bit_cast(f16x8, a4), __builtin_bit_cast(f16x8, Bv[kf]), accA, 0, 0, 0);
                accB = __builtin_amdgcn_mfma_f32_16x16x32_f16(
                    __builtin_bit_cast(f16x8, b4), __builtin_bit_cast(f16x8, Bv[kf]), accB, 0, 0, 0);
            }
            // D: col = lane&15 (all cols identical, B broadcast), row = hb*4 + r.
            // One writer column per tile -> 4 lanes write float4 (rows hb*4..+3).
            if ((l & 15) == 0) {
                const int Ta = 8 * w + 2 * p, Tb = Ta + 1;
                *(f32x4*)(gbuf + Ta * 16 + hb * 4) = accA;
                *(f32x4*)(gbuf + Tb * 16 + hb * 4) = accB;
            }
        }
        __syncthreads();  // bar1: gbuf ready (hbuf reads also drained)

        // Tail: 2 threads per unit compute redundantly (q=0 writes hbuf,
        // q=1 owns the deferred out-store).
        float a0 = gbuf[0 * F + j] + bias0;
        float a1 = gbuf[1 * F + j] + bias1;
        float a2 = gbuf[2 * F + j] + bias2;
        float a3 = gbuf[3 * F + j] + bias3;
        float c2 = sigf(a1) * cj + sigf(a0) * tanhf_fast(a2);
        float h2 = sigf(a3) * tanhf_fast(c2);
        cj = c2;
        if (q == 0) ((__half*)hbuf4)[j] = __float2half(h2);
        hprev = h2;
        __syncthreads();  // bar2: hbuf published for next step
    }
    if (q == 1) {
        __builtin_nontemporal_store(hprev, &out[((size_t)(S - 1) * B + b) * F + j]);
    }
}

extern "C" void kernel_launch(void* const* d_in, const int* in_sizes, int n_in,
                              void* d_out, int out_size, void* d_ws, size_t ws_size,
                              hipStream_t stream) {
    const float* x   = (const float*)d_in[0];
    const float* lf  = (const float*)d_in[1];
    const float* Wi  = (const float*)d_in[2];
    const float* bi  = (const float*)d_in[3];
    const float* Wih = (const float*)d_in[4];
    const float* Whh = (const float*)d_in[5];
    const float* bih = (const float*)d_in[6];
    const float* bhh = (const float*)d_in[7];
    // d_in[8], d_in[9] (Wo, bo): computed-and-discarded in the reference; unused.
    float* out = (float*)d_out;

    float* ws    = (float*)d_ws;
    float* h     = ws;               // 65536 floats
    float* c     = ws + 65536;       // 65536 floats
    float* bias  = ws + 131072;      // 1024 floats
    uint4* Wpk   = (uint4*)(ws + 132096);  // 512 frags x 64 lanes x 16B = 512 KB

    prep_kernel<<<128, 256, 0, stream>>>(Wih, Whh, bih, bhh, Wpk, bias);
    init_kernel<<<B, F, 0, stream>>>(x, Wi, bi, h, c);
    step0_kernel<<<B, 1024, 0, stream>>>(lf, Wih, Whh, bias, h, c, out);
    lstm_main<<<B, 512, 0, stream>>>(Wpk, bias, h, c, out);
}

// Round 5
// 1010.976 us; speedup vs baseline: 1.0526x; 1.0526x over previous
//
#include <hip/hip_runtime.h>
#include <hip/hip_bf16.h>
#include <hip/hip_fp16.h>

#define B 256
#define L 128
#define F 256
#define S 512
#define G4 1024  // 4*F gate rows

typedef _Float16 h2raw __attribute__((ext_vector_type(2)));

__device__ __forceinline__ float fdot2u(unsigned a, unsigned b, float c) {
#if __has_builtin(__builtin_amdgcn_fdot2)
    return __builtin_amdgcn_fdot2(__builtin_bit_cast(h2raw, a), __builtin_bit_cast(h2raw, b), c, false);
#else
    __half2 ah = __builtin_bit_cast(__half2, a), bh = __builtin_bit_cast(__half2, b);
    float2 af = __half22float2(ah), bf = __half22float2(bh);
    return c + af.x * bf.x + af.y * bf.y;
#endif
}

// fast device transcendentals: v_exp_f32 / v_rcp_f32 based
__device__ __forceinline__ float fast_rcp(float x) { return __builtin_amdgcn_rcpf(x); }
__device__ __forceinline__ float sigf(float x) {
    float e = __expf(-x);
    return fast_rcp(1.0f + e);
}
__device__ __forceinline__ float tanhf_fast(float x) {
    x = fminf(fmaxf(x, -15.0f), 15.0f);
    float e = __expf(-2.0f * x);
    return (1.0f - e) * fast_rcp(1.0f + e);
}

template <int CTRL>
__device__ __forceinline__ float dpp_add(float x) {
    int v = __builtin_amdgcn_update_dpp(0, __builtin_bit_cast(int, x), CTRL, 0xF, 0xF, true);
    return x + __builtin_bit_cast(float, v);
}

// Prep v7: pack combined W = W_ih + W_hh for the 1024-thread main kernel.
// Thread mapping: j = tid>>2 (hidden unit), q = tid&3 (k-QUARTER).
// Chunk n in [0,32): n<24 -> register gates g=n>>3 (i,f,g), m=n&7;
//                    n>=24 -> LDS gate g=3 (o), m=n-24.
// Wpk[n*1024+tid] = 4 half2 = k-pairs kp = q*32 + m*4 + {0..3} of row g*256+j.
__global__ void prep_kernel(const float* __restrict__ Wih,
                            const float* __restrict__ Whh,
                            const float* __restrict__ bih,
                            const float* __restrict__ bhh,
                            uint4* __restrict__ Wpk, float* __restrict__ bias_sum) {
    int e = blockIdx.x * blockDim.x + threadIdx.x;  // 32768 elements
    if (e < G4) bias_sum[e] = bih[e] + bhh[e];
    int n = e >> 10, tid = e & 1023;
    int j = tid >> 2, q = tid & 3;
    int g = (n < 24) ? (n >> 3) : 3;
    int m = (n < 24) ? (n & 7) : (n - 24);
    int r = g * F + j;
    int kp0 = q * 32 + m * 4;
    unsigned pk[4];
    #pragma unroll
    for (int i = 0; i < 4; ++i) {
        int k = 2 * (kp0 + i);
        float w0 = Wih[(size_t)r * F + k]     + Whh[(size_t)r * F + k];
        float w1 = Wih[(size_t)r * F + k + 1] + Whh[(size_t)r * F + k + 1];
        pk[i] = __builtin_bit_cast(unsigned, __floats2half2_rn(w0, w1));
    }
    Wpk[(size_t)n * 1024 + tid] = make_uint4(pk[0], pk[1], pk[2], pk[3]);
}

// init = elu(x[0] @ Wi.T + bi) -> h0, c0 (fp32 in workspace), float4 loads
__global__ void init_kernel(const float* __restrict__ x,
                            const float* __restrict__ Wi,
                            const float* __restrict__ bi,
                            float* __restrict__ h, float* __restrict__ c) {
    __shared__ float4 xs4[L / 4];
    int b = blockIdx.x, j = threadIdx.x;
    if (j < L / 4) xs4[j] = ((const float4*)(x + (size_t)b * L))[j];
    __syncthreads();
    float acc = bi[j];
    const float4* wp = (const float4*)(Wi + (size_t)j * L);
    #pragma unroll 8
    for (int k = 0; k < L / 4; ++k) {
        float4 w = wp[k], xv = xs4[k];
        acc += w.x * xv.x + w.y * xv.y + w.z * xv.z + w.w * xv.w;
    }
    float v = acc > 0.0f ? acc : expm1f(acc);
    h[b * F + j] = v;
    c[b * F + j] = v;
}

// Step 0: gates = last_feat @ W_ih.T + h0 @ W_hh.T + bias (fp32 exact path).
__global__ void step0_kernel(const float* __restrict__ lf,
                             const float* __restrict__ Wih,
                             const float* __restrict__ Whh,
                             const float* __restrict__ bias_sum,
                             float* __restrict__ h, float* __restrict__ c,
                             float* __restrict__ out) {
    __shared__ float vecs[2 * F];            // [inp(256) ; h0(256)]
    __shared__ float partial[3][4][F];
    int b = blockIdx.x, tid = threadIdx.x;
    int j = tid & (F - 1), q = tid >> 8;
    if (q == 0) vecs[j] = lf[(size_t)b * F + j];
    else if (q == 1) vecs[F + j] = h[(size_t)b * F + j];
    __syncthreads();
    const float* mat = (q < 2) ? Wih : Whh;
    int ks = (q & 1) * 128;
    const float4* vp = (const float4*)(&vecs[(q >> 1) * F + ks]);
    float a[4] = {0.f, 0.f, 0.f, 0.f};
    #pragma unroll
    for (int g = 0; g < 4; ++g) {
        const float4* wp = (const float4*)(&mat[(size_t)(g * F + j) * F + ks]);
        float acc = 0.f;
        #pragma unroll 8
        for (int i = 0; i < 32; ++i) {
            float4 w = wp[i], v = vp[i];
            acc += w.x * v.x + w.y * v.y + w.z * v.z + w.w * v.w;
        }
        a[g] = acc;
    }
    if (q > 0) {
        #pragma unroll
        for (int g = 0; g < 4; ++g) partial[q - 1][g][j] = a[g];
    }
    __syncthreads();
    if (q == 0) {
        #pragma unroll
        for (int g = 0; g < 4; ++g) {
            for (int p = 0; p < 3; ++p) a[g] += partial[p][g][j];
            a[g] += bias_sum[g * F + j];
        }
        float c0v = c[(size_t)b * F + j];
        float c1v = sigf(a[1]) * c0v + sigf(a[0]) * tanhf_fast(a[2]);
        float h1v = sigf(a[3]) * tanhf_fast(c1v);
        h[(size_t)b * F + j] = h1v;
        c[(size_t)b * F + j] = c1v;
        out[(size_t)b * F + j] = h1v;  // t=0 row
    }
}

// Main recurrence v7: OCCUPANCY build. 1024 threads (16 waves) per batch
// element, j = tid>>2 (unit), q = tid&3 (k-quarter). Rationale from R0-R4
// counters: every variant ran at 1.5-1.9x its busiest-pipe budget with
// OccupancyPercent ~23% -- 2 waves/SIMD cannot hide LDS/VALU latency. The
// cap was register-driven: R3's 48-uint4 weight array = 192 AGPRs on top of
// 128 VGPRs (320 total -> ~7 waves/CU) AND paid a v_accvgpr_read shuttle per
// fdot2 operand. Quarter-split k halves the resident weights to 24 uint4 =
// 96 dwords -> total regs <= 128 (launch_bounds-enforced), so:
//   * 16 waves/CU resident (4/SIMD, 2x TLP),
//   * weights live in true VGPRs -> zero shuttle instructions.
// Gate o streams from LDS chunk-major (lds_wo[m][tid]: lane banks 4*(tid&7),
// 8 lanes/bank-group = b128 minimum, conflict-free -- same pattern as R3's
// measured-zero-conflict layout). hbuf quarters padded to 144 B so the four
// 16-lane broadcast groups start at bank-groups 0/4/8/12 (disjoint).
// Reduce: DPP quad xor1 (0xB1) + xor2 (0x4E) -- lanes of a quad are the 4
// k-quarters of one unit. Deferred out-store + single-barrier ping-pong
// retained from R3 (both measured wins).
__launch_bounds__(1024, 1)
__global__ void lstm_main(const uint4* __restrict__ Wpk,
                          const float* __restrict__ bias_sum,
                          const float* __restrict__ h_in,
                          const float* __restrict__ c_in,
                          float* __restrict__ out) {
    int b = blockIdx.x;
    int tid = threadIdx.x;
    int j = tid >> 2;
    int q = tid & 3;

    __shared__ uint4 lds_wo[8][1024];     // gate-o weights, 128 KB
    __shared__ unsigned hbuf[2][4 * 36];  // 2 bufs x 4 quarters x (32+4 pad) dwords

    // One-time: gates i,f,g into registers (96 dwords), gate o into LDS.
    uint4 wr[24];
    #pragma unroll
    for (int n = 0; n < 24; ++n) wr[n] = Wpk[(size_t)n * 1024 + tid];
    #pragma unroll
    for (int m = 0; m < 8; ++m) lds_wo[m][tid] = Wpk[(size_t)(24 + m) * 1024 + tid];

    float bias0 = bias_sum[0 * F + j];
    float bias1 = bias_sum[1 * F + j];
    float bias2 = bias_sum[2 * F + j];
    float bias3 = bias_sum[3 * F + j];
    float cj = c_in[(size_t)b * F + j];

    // initial h fill: h value k -> quarter k>>6 (36-dword stride), slot k&63
    if (tid < F) {
        __half* hp = (__half*)&hbuf[0][(tid >> 6) * 36];
        hp[tid & 63] = __float2half(h_in[(size_t)b * F + tid]);
    }
    __syncthreads();

    int cur = 0;
    float hprev = 0.f;  // deferred out-store value (q==1 path)
    for (int t = 1; t < S; ++t) {
        const uint4* hbq = (const uint4*)&hbuf[cur][q * 36];
        // deferred store of previous step's h row: issued here, drained by
        // the end-of-step barrier ~a full step later -> hidden.
        if (q == 1 && t > 1) {
            __builtin_nontemporal_store(hprev, &out[((size_t)(t - 1) * B + b) * F + j]);
        }
        float a0 = 0.f, a1 = 0.f, a2 = 0.f, a3 = 0.f;
        #pragma unroll
        for (int m = 0; m < 8; ++m) {
            uint4 hv = hbq[m];            // 4 h2 pairs of this thread's k-quarter
            uint4 w3 = lds_wo[m][tid];    // gate-o chunk (streamed)
            uint4 w0 = wr[m];
            uint4 w1 = wr[8 + m];
            uint4 w2 = wr[16 + m];
            a0 = fdot2u(w0.x, hv.x, a0); a0 = fdot2u(w0.y, hv.y, a0);
            a0 = fdot2u(w0.z, hv.z, a0); a0 = fdot2u(w0.w, hv.w, a0);
            a1 = fdot2u(w1.x, hv.x, a1); a1 = fdot2u(w1.y, hv.y, a1);
            a1 = fdot2u(w1.z, hv.z, a1); a1 = fdot2u(w1.w, hv.w, a1);
            a2 = fdot2u(w2.x, hv.x, a2); a2 = fdot2u(w2.y, hv.y, a2);
            a2 = fdot2u(w2.z, hv.z, a2); a2 = fdot2u(w2.w, hv.w, a2);
            a3 = fdot2u(w3.x, hv.x, a3); a3 = fdot2u(w3.y, hv.y, a3);
            a3 = fdot2u(w3.z, hv.z, a3); a3 = fdot2u(w3.w, hv.w, a3);
        }

        // quad reduction over the 4 k-quarters; all 4 lanes get full sums
        a0 = dpp_add<0x4E>(dpp_add<0xB1>(a0)) + bias0;
        a1 = dpp_add<0x4E>(dpp_add<0xB1>(a1)) + bias1;
        a2 = dpp_add<0x4E>(dpp_add<0xB1>(a2)) + bias2;
        a3 = dpp_add<0x4E>(dpp_add<0xB1>(a3)) + bias3;
        float c2 = sigf(a1) * cj + sigf(a0) * tanhf_fast(a2);
        float h2 = sigf(a3) * tanhf_fast(c2);
        cj = c2;
        if (q == 0) {
            __half* hp = (__half*)&hbuf[cur ^ 1][(j >> 6) * 36];
            hp[j & 63] = __float2half(h2);
        }
        hprev = h2;
        __syncthreads();
        cur ^= 1;
    }
    if (q == 1) {
        __builtin_nontemporal_store(hprev, &out[((size_t)(S - 1) * B + b) * F + j]);
    }
}

extern "C" void kernel_launch(void* const* d_in, const int* in_sizes, int n_in,
                              void* d_out, int out_size, void* d_ws, size_t ws_size,
                              hipStream_t stream) {
    const float* x   = (const float*)d_in[0];
    const float* lf  = (const float*)d_in[1];
    const float* Wi  = (const float*)d_in[2];
    const float* bi  = (const float*)d_in[3];
    const float* Wih = (const float*)d_in[4];
    const float* Whh = (const float*)d_in[5];
    const float* bih = (const float*)d_in[6];
    const float* bhh = (const float*)d_in[7];
    // d_in[8], d_in[9] (Wo, bo): computed-and-discarded in the reference; unused.
    float* out = (float*)d_out;

    float* ws    = (float*)d_ws;
    float* h     = ws;               // 65536 floats
    float* c     = ws + 65536;       // 65536 floats
    float* bias  = ws + 131072;      // 1024 floats
    uint4* Wpk   = (uint4*)(ws + 132096);  // 32 chunks x 1024 x 16B = 512 KB

    prep_kernel<<<128, 256, 0, stream>>>(Wih, Whh, bih, bhh, Wpk, bias);
    init_kernel<<<B, F, 0, stream>>>(x, Wi, bi, h, c);
    step0_kernel<<<B, 1024, 0, stream>>>(lf, Wih, Whh, bias, h, c, out);
    lstm_main<<<B, 1024, 0, stream>>>(Wpk, bias, h, c, out);
}